// Round 4
// baseline (590.527 us; speedup 1.0000x reference)
//
#include <hip/hip_runtime.h>

// MultiRelGraphTransformer on MI355X — round 4.
// Changes vs r3: spmm+gemm_ln fused into k_fused (relation-aligned K chunks:
// gather rel-r 64-row sums -> LDS bf16 -> MFMA vs Wt chunk). G intermediate
// eliminated (-122 MB/layer). H ping-pongs HB -> HB2 -> out (no in-place race).

#define NNODES 20000
#define NB     4
#define BROWS  (NB * NNODES)   // 80000
#define DN     64
#define DM     128
#define NE     160000
#define CAP    64              // bucket capacity per (relation,dst); Poisson(8)
#define LN_EPS 1e-5f
#define TPB    313             // 64-row tiles per batch (last overlaps: n0=19936)

typedef __attribute__((ext_vector_type(8))) short bf16x8;
typedef __attribute__((ext_vector_type(4))) float f32x4;

__device__ inline float bf2f(unsigned short u) {
    union { unsigned int i; float f; } x; x.i = ((unsigned int)u) << 16; return x.f;
}
__device__ inline unsigned short f2bf(float f) {
    union { float f; unsigned int i; } x; x.f = f;
    unsigned int r = x.i + 0x7FFFu + ((x.i >> 16) & 1u);
    return (unsigned short)(r >> 16);
}

// ---------- K1: counting-sort into fixed buckets (cursor doubles as deg) ----------
__global__ void k_scatter(const int* __restrict__ ei0, const int* __restrict__ ei1,
                          const int* __restrict__ ei2, int* __restrict__ cursor,
                          int* __restrict__ srcs) {
    int tid = blockIdx.x * blockDim.x + threadIdx.x;
    if (tid >= 3 * NE) return;
    int r = tid / NE, e = tid - r * NE;
    const int* ei = (r == 0) ? ei0 : ((r == 1) ? ei1 : ei2);
    int src = ei[e], dst = ei[NE + e];
    int p = atomicAdd(&cursor[r * NNODES + dst], 1);
    if (p < CAP) srcs[(r * NNODES + dst) * CAP + p] = src;
}

// ---------- K2: S[r][dst][16] += ea_r[e]  (coalesced, low-contention atomics) ----------
__global__ void k_ea(const int* __restrict__ ei0, const int* __restrict__ ei1,
                     const float* __restrict__ ea0, const float* __restrict__ ea1,
                     float* __restrict__ S) {
    int tid = blockIdx.x * blockDim.x + threadIdx.x;
    if (tid >= 2 * NE * 4) return;
    int c4 = (tid & 3) * 4;
    int er = tid >> 2;
    int r = er / NE, e = er - r * NE;
    const float* ea = r ? ea1 : ea0;
    const int*   ei = r ? ei1 : ei0;
    int dst = ei[NE + e];
    float4 v = *(const float4*)(ea + (size_t)e * 16 + c4);
    float* sp = S + ((size_t)(r * NNODES + dst)) * 16 + c4;
    atomicAdd(sp + 0, v.x); atomicAdd(sp + 1, v.y);
    atomicAdd(sp + 2, v.z); atomicAdd(sp + 3, v.w);
}

// ---------- K3: transpose node_W -> Wt[l][n][k] bf16 (K=384) ----------
__global__ __launch_bounds__(256) void k_wprep(const float* __restrict__ W,
                                               unsigned short* __restrict__ Wt) {
    int lin = blockIdx.x * 256 + threadIdx.x;   // 2*3*128*128 = 98304
    int n = lin & 127;
    int rest = lin >> 7;
    int kk = rest & 127;
    int lr = rest >> 7;
    int r = lr % 3, l = lr / 3;
    float v = W[(((size_t)(l * 3 + r) * 128) + kk) * 128 + n];
    Wt[((size_t)(l * 128 + n)) * 384 + r * 128 + kk] = f2bf(v);
}

// ---------- K4: input projection HB = bf16(node_feat @ in_W + in_b) ----------
__global__ __launch_bounds__(256) void k_proj(const float* __restrict__ X,
                                              const float* __restrict__ W,
                                              const float* __restrict__ bias,
                                              unsigned short* __restrict__ HB) {
    __shared__ float Xs[64][68];
    __shared__ float Ws[64][128];
    int t = threadIdx.x;
    int m0 = blockIdx.x * 64;
#pragma unroll
    for (int i = 0; i < 4; ++i) {
        int lin = t + 256 * i;
        int row = lin >> 4, c4 = lin & 15;
        float4 v = *(const float4*)(X + (size_t)(m0 + row) * DN + c4 * 4);
        *(float4*)&Xs[row][c4 * 4] = v;
    }
#pragma unroll
    for (int i = 0; i < 8; ++i) {
        int lin = t + 256 * i;
        int row = lin >> 5, c4 = lin & 31;
        *(float4*)&Ws[row][c4 * 4] = *(const float4*)(W + (size_t)row * DM + c4 * 4);
    }
    __syncthreads();
    int tc = t & 31, tr = t >> 5;
    float acc[8][4];
#pragma unroll
    for (int i = 0; i < 8; ++i)
#pragma unroll
        for (int j = 0; j < 4; ++j) acc[i][j] = 0.f;

    for (int kk = 0; kk < 64; kk += 4) {
        float4 w0 = *(float4*)&Ws[kk + 0][tc * 4];
        float4 w1 = *(float4*)&Ws[kk + 1][tc * 4];
        float4 w2 = *(float4*)&Ws[kk + 2][tc * 4];
        float4 w3 = *(float4*)&Ws[kk + 3][tc * 4];
#pragma unroll
        for (int i = 0; i < 8; ++i) {
            float4 g = *(float4*)&Xs[tr * 8 + i][kk];
            acc[i][0] = fmaf(g.x, w0.x, fmaf(g.y, w1.x, fmaf(g.z, w2.x, fmaf(g.w, w3.x, acc[i][0]))));
            acc[i][1] = fmaf(g.x, w0.y, fmaf(g.y, w1.y, fmaf(g.z, w2.y, fmaf(g.w, w3.y, acc[i][1]))));
            acc[i][2] = fmaf(g.x, w0.z, fmaf(g.y, w1.z, fmaf(g.z, w2.z, fmaf(g.w, w3.z, acc[i][2]))));
            acc[i][3] = fmaf(g.x, w0.w, fmaf(g.y, w1.w, fmaf(g.z, w2.w, fmaf(g.w, w3.w, acc[i][3]))));
        }
    }
    float4 b4 = *(const float4*)(bias + tc * 4);
#pragma unroll
    for (int i = 0; i < 8; ++i) {
        int row = m0 + tr * 8 + i;
        ushort4 o;
        o.x = f2bf(acc[i][0] + b4.x); o.y = f2bf(acc[i][1] + b4.y);
        o.z = f2bf(acc[i][2] + b4.z); o.w = f2bf(acc[i][3] + b4.w);
        *(ushort4*)(HB + (size_t)row * DM + tc * 4) = o;
    }
}

// ---------- K5: SB[l][n][128] for both layers ----------
__global__ __launch_bounds__(128) void k_sb(const int* __restrict__ deg,
                                            const float* __restrict__ S,
                                            const float* __restrict__ node_b_all,
                                            const float* __restrict__ edge_W_all,
                                            const float* __restrict__ edge_b_all,
                                            float* __restrict__ SBall) {
    int l = blockIdx.x / NNODES, n = blockIdx.x - l * NNODES;
    int j = threadIdx.x;
    const float* node_b = node_b_all + (size_t)l * 3 * DM;
    const float* edge_W = edge_W_all + (size_t)l * 2 * 16 * DM;
    const float* edge_b = edge_b_all + (size_t)l * 2 * DM;
    __shared__ float sS[2][16];
    __shared__ int sdeg[3];
    if (j < 32) sS[j >> 4][j & 15] = S[(((j >> 4)) * NNODES + n) * 16 + (j & 15)];
    if (j >= 32 && j < 35) sdeg[j - 32] = deg[(j - 32) * NNODES + n];
    __syncthreads();
    float val = 0.f;
#pragma unroll
    for (int r = 0; r < 3; ++r) val += (float)sdeg[r] * node_b[r * DM + j];
#pragma unroll
    for (int r = 0; r < 2; ++r) {
        val += (float)sdeg[r] * edge_b[r * DM + j];
#pragma unroll
        for (int k = 0; k < 16; ++k) val += sS[r][k] * edge_W[(r * 16 + k) * DM + j];
    }
    SBall[((size_t)l * NNODES + n) * DM + j] = val;
}

// ---------- K6: fused SpMM + MFMA GEMM + bias + residual + ReLU + LN ----------
// Per relation rc: gather rel-rc 64-row sums -> Gs (bf16), stage Wt chunk -> Ws,
// MFMA 4 k-tiles. A-frag A[m=lane&15][k=q*8+j]; C/D col=lane&15,row=q*4+reg.
__global__ __launch_bounds__(256) void k_fused(const unsigned short* __restrict__ HBprev,
                                               const int* __restrict__ deg,
                                               const int* __restrict__ srcs,
                                               const unsigned short* __restrict__ Wt,   // [128][384]
                                               const float* __restrict__ SB,            // [NNODES][128]
                                               unsigned short* __restrict__ HBnext,
                                               const float* __restrict__ lng,
                                               const float* __restrict__ lnb,
                                               float* __restrict__ out, int write_f32) {
    __shared__ __align__(16) unsigned short Gs[64][136];    // 68 dw stride: 2-way only
    __shared__ __align__(16) unsigned short Ws[128][136];
    // block -> (batch, node tile); XCD affinity: xcd = blockIdx&7 -> batch
    int s = blockIdx.x & 7, qb = blockIdx.x >> 3;
    int bb = s >> 1;
    int idx = qb * 2 + (s & 1);
    if (idx >= TPB) return;
    int n0 = idx * 64; if (n0 > NNODES - 64) n0 = NNODES - 64;   // overlap tail tile
    size_t row0 = (size_t)bb * NNODES + n0;
    const unsigned short* Hb = HBprev + (size_t)bb * NNODES * DM;

    int t = threadIdx.x;
    int w = t >> 6, lane = t & 63;
    int q = lane >> 4, lm = lane & 15;
    int g32 = t >> 5, lane32 = t & 31, c4 = lane32 * 4;

    f32x4 acc[8];
#pragma unroll
    for (int ct = 0; ct < 8; ++ct) acc[ct] = (f32x4){0.f, 0.f, 0.f, 0.f};

    for (int rc = 0; rc < 3; ++rc) {
        // stage Wt chunk: 128 rows x 128 k
#pragma unroll
        for (int i = 0; i < 8; ++i) {
            int lin = t + 256 * i;            // 0..2047
            int row = lin >> 4, seg = lin & 15;
            *(uint4*)&Ws[row][seg * 8] =
                *(const uint4*)(Wt + (size_t)row * 384 + rc * 128 + seg * 8);
        }
        // gather: 8 groups x 32 lanes; each group 8 rows
#pragma unroll
        for (int i = 0; i < 8; ++i) {
            int lr = g32 + i * 8;
            int n = n0 + lr;
            int dg = deg[rc * NNODES + n];
            if (dg > CAP) dg = CAP;
            const int* bk = srcs + (size_t)(rc * NNODES + n) * CAP;
            float a0 = 0.f, a1 = 0.f, a2 = 0.f, a3 = 0.f;
            int j = 0;
            for (; j + 3 < dg; j += 4) {
                int4 s4 = *(const int4*)&bk[j];
                ushort4 v0 = *(const ushort4*)(Hb + (size_t)s4.x * DM + c4);
                ushort4 v1 = *(const ushort4*)(Hb + (size_t)s4.y * DM + c4);
                ushort4 v2 = *(const ushort4*)(Hb + (size_t)s4.z * DM + c4);
                ushort4 v3 = *(const ushort4*)(Hb + (size_t)s4.w * DM + c4);
                a0 += bf2f(v0.x) + bf2f(v1.x) + bf2f(v2.x) + bf2f(v3.x);
                a1 += bf2f(v0.y) + bf2f(v1.y) + bf2f(v2.y) + bf2f(v3.y);
                a2 += bf2f(v0.z) + bf2f(v1.z) + bf2f(v2.z) + bf2f(v3.z);
                a3 += bf2f(v0.w) + bf2f(v1.w) + bf2f(v2.w) + bf2f(v3.w);
            }
            for (; j < dg; ++j) {
                int s0 = bk[j];
                ushort4 v0 = *(const ushort4*)(Hb + (size_t)s0 * DM + c4);
                a0 += bf2f(v0.x); a1 += bf2f(v0.y); a2 += bf2f(v0.z); a3 += bf2f(v0.w);
            }
            ushort4 hv;
            hv.x = f2bf(a0); hv.y = f2bf(a1); hv.z = f2bf(a2); hv.w = f2bf(a3);
            *(ushort4*)&Gs[lr][c4] = hv;
        }
        __syncthreads();
#pragma unroll
        for (int kt = 0; kt < 4; ++kt) {
            bf16x8 a = *(const bf16x8*)&Gs[w * 16 + lm][kt * 32 + q * 8];
#pragma unroll
            for (int ct = 0; ct < 8; ++ct) {
                bf16x8 bf = *(const bf16x8*)&Ws[ct * 16 + lm][kt * 32 + q * 8];
                acc[ct] = __builtin_amdgcn_mfma_f32_16x16x32_bf16(a, bf, acc[ct], 0, 0, 0);
            }
        }
        __syncthreads();
    }

    // epilogue: x = H + relu(acc + SB); LayerNorm over 128 cols
    float gc[8], bc[8];
#pragma unroll
    for (int ct = 0; ct < 8; ++ct) {
        int col = ct * 16 + lm;
        gc[ct] = lng[col]; bc[ct] = lnb[col];
    }
#pragma unroll
    for (int reg = 0; reg < 4; ++reg) {
        int lr = w * 16 + q * 4 + reg;
        size_t row = row0 + lr;
        int n = n0 + lr;
        float xv[8];
        float s1 = 0.f, s2 = 0.f;
#pragma unroll
        for (int ct = 0; ct < 8; ++ct) {
            int col = ct * 16 + lm;
            float h  = bf2f(HBprev[row * DM + col]);
            float sb = SB[(size_t)n * DM + col];
            float v = h + fmaxf(acc[ct][reg] + sb, 0.f);
            xv[ct] = v; s1 += v; s2 += v * v;
        }
#pragma unroll
        for (int m = 1; m <= 8; m <<= 1) {
            s1 += __shfl_xor(s1, m, 64);
            s2 += __shfl_xor(s2, m, 64);
        }
        float mu  = s1 * (1.f / 128.f);
        float var = s2 * (1.f / 128.f) - mu * mu;
        float inv = rsqrtf(var + LN_EPS);
        if (write_f32) {
#pragma unroll
            for (int ct = 0; ct < 8; ++ct) {
                int col = ct * 16 + lm;
                out[row * DM + col] = (xv[ct] - mu) * inv * gc[ct] + bc[ct];
            }
        } else {
#pragma unroll
            for (int ct = 0; ct < 8; ++ct) {
                int col = ct * 16 + lm;
                HBnext[row * DM + col] = f2bf((xv[ct] - mu) * inv * gc[ct] + bc[ct]);
            }
        }
    }
}

extern "C" void kernel_launch(void* const* d_in, const int* in_sizes, int n_in,
                              void* d_out, int out_size, void* d_ws, size_t ws_size,
                              hipStream_t stream) {
    const float* node_feat = (const float*)d_in[0];
    const float* in_W   = (const float*)d_in[1];
    const float* in_b   = (const float*)d_in[2];
    const float* node_W = (const float*)d_in[3];   // [2][3][128][128]
    const float* node_b = (const float*)d_in[4];   // [2][3][128]
    const float* edge_W = (const float*)d_in[5];   // [2][2][16][128]
    const float* edge_b = (const float*)d_in[6];   // [2][2][128]
    const float* ln_g   = (const float*)d_in[7];   // [2][128]
    const float* ln_b   = (const float*)d_in[8];   // [2][128]
    const float* ea0    = (const float*)d_in[9];
    const float* ea1    = (const float*)d_in[10];
    const int*   ei0    = (const int*)d_in[11];
    const int*   ei1    = (const int*)d_in[12];
    const int*   ei2    = (const int*)d_in[13];
    float* out = (float*)d_out;

    char* ws = (char*)d_ws;
    size_t off = 0;
    auto alloc = [&](size_t bytes) -> void* {
        void* p = ws + off;
        off = (off + bytes + 255) & ~(size_t)255;
        return p;
    };
    unsigned short* HB     = (unsigned short*)alloc((size_t)BROWS * DM * 2);   // 20.5 MB
    unsigned short* HB2    = (unsigned short*)alloc((size_t)BROWS * DM * 2);   // 20.5 MB
    float*          SB     = (float*)alloc((size_t)2 * NNODES * DM * 4);       // 20.5 MB
    int*            cursor = (int*)alloc((size_t)3 * NNODES * 4);              // zeroed
    float*          S      = (float*)alloc((size_t)2 * NNODES * 16 * 4);       // zeroed
    int*            srcs   = (int*)alloc((size_t)3 * NNODES * CAP * 4);        // 15 MB
    unsigned short* Wt     = (unsigned short*)alloc((size_t)2 * 128 * 384 * 2);

    // cursor and S are adjacent (modulo 256-pad) -> one memset covering both
    hipMemsetAsync(cursor, 0, (size_t)((char*)srcs - (char*)cursor), stream);

    k_scatter<<<(3 * NE + 255) / 256, 256, 0, stream>>>(ei0, ei1, ei2, cursor, srcs);
    k_ea<<<(2 * NE * 4 + 255) / 256, 256, 0, stream>>>(ei0, ei1, ea0, ea1, S);
    k_wprep<<<384, 256, 0, stream>>>(node_W, Wt);
    k_proj<<<BROWS / 64, 256, 0, stream>>>(node_feat, in_W, in_b, HB);
    k_sb<<<2 * NNODES, 128, 0, stream>>>(cursor, S, node_b, edge_W, edge_b, SB);

    const int grid = 8 * ((TPB + 1) / 2);   // 1256 blocks; 4 return early
    k_fused<<<grid, 256, 0, stream>>>(HB, cursor, srcs, Wt, SB, HB2,
                                      ln_g, ln_b, out, 0);
    k_fused<<<grid, 256, 0, stream>>>(HB2, cursor, srcs, Wt + (size_t)128 * 384,
                                      SB + (size_t)NNODES * DM, HB2 /*unused*/,
                                      ln_g + DM, ln_b + DM, out, 1);
}

// Round 5
// 572.963 us; speedup vs baseline: 1.0307x; 1.0307x over previous
//
#include <hip/hip_runtime.h>

// MultiRelGraphTransformer on MI355X — round 5.
// Fusion v2: spmm+gemm+LN fused, but Ws staging ELIMINATED (B-frags read
// directly from global Wt, L1/L2-resident 96 KB) -> LDS 52->17.4 KB ->
// ~6 blocks/CU (r4 fusion died at 2-3 blocks: occupancy 26%, no latency
// hiding). k_ea atomics reverted to r2-style bucket walk (eids in scatter).

#define NNODES 20000
#define NB     4
#define BROWS  (NB * NNODES)   // 80000
#define DN     64
#define DM     128
#define NE     160000
#define CAP    64              // bucket capacity per (relation,dst); Poisson(8)
#define LN_EPS 1e-5f
#define TPB    313             // 64-row tiles per batch (last overlaps: n0=19936)

typedef __attribute__((ext_vector_type(8))) short bf16x8;
typedef __attribute__((ext_vector_type(4))) float f32x4;

__device__ inline float bf2f(unsigned short u) {
    union { unsigned int i; float f; } x; x.i = ((unsigned int)u) << 16; return x.f;
}
__device__ inline unsigned short f2bf(float f) {
    union { float f; unsigned int i; } x; x.f = f;
    unsigned int r = x.i + 0x7FFFu + ((x.i >> 16) & 1u);
    return (unsigned short)(r >> 16);
}

// ---------- K1: counting-sort into fixed buckets (cursor doubles as deg) ----------
__global__ void k_scatter(const int* __restrict__ ei0, const int* __restrict__ ei1,
                          const int* __restrict__ ei2, int* __restrict__ cursor,
                          int* __restrict__ srcs, int* __restrict__ eids) {
    int tid = blockIdx.x * blockDim.x + threadIdx.x;
    if (tid >= 3 * NE) return;
    int r = tid / NE, e = tid - r * NE;
    const int* ei = (r == 0) ? ei0 : ((r == 1) ? ei1 : ei2);
    int src = ei[e], dst = ei[NE + e];
    int p = atomicAdd(&cursor[r * NNODES + dst], 1);
    if (p < CAP) {
        srcs[(r * NNODES + dst) * CAP + p] = src;
        if (r < 2) eids[(r * NNODES + dst) * CAP + p] = e;
    }
}

// ---------- K2: S[r][n][16] = sum of ea_r over incoming edges (bucket walk) ----------
__global__ __launch_bounds__(256) void k_sgather(const int* __restrict__ deg,
                                                 const int* __restrict__ eids,
                                                 const float* __restrict__ ea0,
                                                 const float* __restrict__ ea1,
                                                 float* __restrict__ S) {
    int task = blockIdx.x * 4 + (threadIdx.x >> 6);   // 0 .. 2*NNODES-1
    int r = task / NNODES;
    const float* ea = r ? ea1 : ea0;
    int lane = threadIdx.x & 63;
    int k = lane & 15, sub = lane >> 4;
    int dg = deg[task]; if (dg > CAP) dg = CAP;
    const int* bk = eids + (size_t)task * CAP;
    float acc = 0.f;
    for (int j = sub; j < dg; j += 4) {
        int e = bk[j];
        acc += ea[e * 16 + k];
    }
    acc += __shfl_xor(acc, 16, 64);
    acc += __shfl_xor(acc, 32, 64);
    if (lane < 16) S[(size_t)task * 16 + k] = acc;
}

// ---------- K3: transpose node_W -> Wt[l][n][k] bf16 (K=384) ----------
__global__ __launch_bounds__(256) void k_wprep(const float* __restrict__ W,
                                               unsigned short* __restrict__ Wt) {
    int lin = blockIdx.x * 256 + threadIdx.x;   // 2*3*128*128 = 98304
    int n = lin & 127;
    int rest = lin >> 7;
    int kk = rest & 127;
    int lr = rest >> 7;
    int r = lr % 3, l = lr / 3;
    float v = W[(((size_t)(l * 3 + r) * 128) + kk) * 128 + n];
    Wt[((size_t)(l * 128 + n)) * 384 + r * 128 + kk] = f2bf(v);
}

// ---------- K4: input projection HB = bf16(node_feat @ in_W + in_b) ----------
__global__ __launch_bounds__(256) void k_proj(const float* __restrict__ X,
                                              const float* __restrict__ W,
                                              const float* __restrict__ bias,
                                              unsigned short* __restrict__ HB) {
    __shared__ float Xs[64][68];
    __shared__ float Ws[64][128];
    int t = threadIdx.x;
    int m0 = blockIdx.x * 64;
#pragma unroll
    for (int i = 0; i < 4; ++i) {
        int lin = t + 256 * i;
        int row = lin >> 4, c4 = lin & 15;
        float4 v = *(const float4*)(X + (size_t)(m0 + row) * DN + c4 * 4);
        *(float4*)&Xs[row][c4 * 4] = v;
    }
#pragma unroll
    for (int i = 0; i < 8; ++i) {
        int lin = t + 256 * i;
        int row = lin >> 5, c4 = lin & 31;
        *(float4*)&Ws[row][c4 * 4] = *(const float4*)(W + (size_t)row * DM + c4 * 4);
    }
    __syncthreads();
    int tc = t & 31, tr = t >> 5;
    float acc[8][4];
#pragma unroll
    for (int i = 0; i < 8; ++i)
#pragma unroll
        for (int j = 0; j < 4; ++j) acc[i][j] = 0.f;

    for (int kk = 0; kk < 64; kk += 4) {
        float4 w0 = *(float4*)&Ws[kk + 0][tc * 4];
        float4 w1 = *(float4*)&Ws[kk + 1][tc * 4];
        float4 w2 = *(float4*)&Ws[kk + 2][tc * 4];
        float4 w3 = *(float4*)&Ws[kk + 3][tc * 4];
#pragma unroll
        for (int i = 0; i < 8; ++i) {
            float4 g = *(float4*)&Xs[tr * 8 + i][kk];
            acc[i][0] = fmaf(g.x, w0.x, fmaf(g.y, w1.x, fmaf(g.z, w2.x, fmaf(g.w, w3.x, acc[i][0]))));
            acc[i][1] = fmaf(g.x, w0.y, fmaf(g.y, w1.y, fmaf(g.z, w2.y, fmaf(g.w, w3.y, acc[i][1]))));
            acc[i][2] = fmaf(g.x, w0.z, fmaf(g.y, w1.z, fmaf(g.z, w2.z, fmaf(g.w, w3.z, acc[i][2]))));
            acc[i][3] = fmaf(g.x, w0.w, fmaf(g.y, w1.w, fmaf(g.z, w2.w, fmaf(g.w, w3.w, acc[i][3]))));
        }
    }
    float4 b4 = *(const float4*)(bias + tc * 4);
#pragma unroll
    for (int i = 0; i < 8; ++i) {
        int row = m0 + tr * 8 + i;
        ushort4 o;
        o.x = f2bf(acc[i][0] + b4.x); o.y = f2bf(acc[i][1] + b4.y);
        o.z = f2bf(acc[i][2] + b4.z); o.w = f2bf(acc[i][3] + b4.w);
        *(ushort4*)(HB + (size_t)row * DM + tc * 4) = o;
    }
}

// ---------- K5: SB[l][n][128] for both layers ----------
__global__ __launch_bounds__(128) void k_sb(const int* __restrict__ deg,
                                            const float* __restrict__ S,
                                            const float* __restrict__ node_b_all,
                                            const float* __restrict__ edge_W_all,
                                            const float* __restrict__ edge_b_all,
                                            float* __restrict__ SBall) {
    int l = blockIdx.x / NNODES, n = blockIdx.x - l * NNODES;
    int j = threadIdx.x;
    const float* node_b = node_b_all + (size_t)l * 3 * DM;
    const float* edge_W = edge_W_all + (size_t)l * 2 * 16 * DM;
    const float* edge_b = edge_b_all + (size_t)l * 2 * DM;
    __shared__ float sS[2][16];
    __shared__ int sdeg[3];
    if (j < 32) sS[j >> 4][j & 15] = S[(((j >> 4)) * NNODES + n) * 16 + (j & 15)];
    if (j >= 32 && j < 35) sdeg[j - 32] = deg[(j - 32) * NNODES + n];
    __syncthreads();
    float val = 0.f;
#pragma unroll
    for (int r = 0; r < 3; ++r) val += (float)sdeg[r] * node_b[r * DM + j];
#pragma unroll
    for (int r = 0; r < 2; ++r) {
        val += (float)sdeg[r] * edge_b[r * DM + j];
#pragma unroll
        for (int k = 0; k < 16; ++k) val += sS[r][k] * edge_W[(r * 16 + k) * DM + j];
    }
    SBall[((size_t)l * NNODES + n) * DM + j] = val;
}

// ---------- K6: fused SpMM + MFMA GEMM + bias + residual + ReLU + LN (v2) ----------
// LDS holds only Gs (gathered A-tile). B-frags stream from global Wt (L1/L2
// resident, 96 KB). A-frag A[m=lane&15][k=q*8+j]; C/D col=lane&15,row=q*4+reg.
__global__ __launch_bounds__(256, 6) void k_fused(const unsigned short* __restrict__ HBprev,
                                                  const int* __restrict__ deg,
                                                  const int* __restrict__ srcs,
                                                  const unsigned short* __restrict__ Wt,  // [128][384]
                                                  const float* __restrict__ SB,           // [NNODES][128]
                                                  unsigned short* __restrict__ HBnext,
                                                  const float* __restrict__ lng,
                                                  const float* __restrict__ lnb,
                                                  float* __restrict__ out, int write_f32) {
    __shared__ __align__(16) unsigned short Gs[64][136];    // 17.4 KB total LDS
    // block -> (batch, node tile); XCD affinity: xcd = blockIdx&7 -> batch
    int s = blockIdx.x & 7, qb = blockIdx.x >> 3;
    int bb = s >> 1;
    int idx = qb * 2 + (s & 1);
    if (idx >= TPB) return;
    int n0 = idx * 64; if (n0 > NNODES - 64) n0 = NNODES - 64;   // overlap tail tile
    size_t row0 = (size_t)bb * NNODES + n0;
    const unsigned short* Hb = HBprev + (size_t)bb * NNODES * DM;

    int t = threadIdx.x;
    int w = t >> 6, lane = t & 63;
    int q = lane >> 4, lm = lane & 15;
    int g32 = t >> 5, lane32 = t & 31, c4 = lane32 * 4;

    f32x4 acc[8];
#pragma unroll
    for (int ct = 0; ct < 8; ++ct) acc[ct] = (f32x4){0.f, 0.f, 0.f, 0.f};

    for (int rc = 0; rc < 3; ++rc) {
        // gather: 8 groups x 32 lanes; each group 8 rows (full 128-col rel sums)
#pragma unroll
        for (int i = 0; i < 8; ++i) {
            int lr = g32 + i * 8;
            int n = n0 + lr;
            int dg = deg[rc * NNODES + n];
            if (dg > CAP) dg = CAP;
            const int* bk = srcs + (size_t)(rc * NNODES + n) * CAP;
            float a0 = 0.f, a1 = 0.f, a2 = 0.f, a3 = 0.f;
            int j = 0;
            for (; j + 3 < dg; j += 4) {
                int4 s4 = *(const int4*)&bk[j];
                ushort4 v0 = *(const ushort4*)(Hb + (size_t)s4.x * DM + c4);
                ushort4 v1 = *(const ushort4*)(Hb + (size_t)s4.y * DM + c4);
                ushort4 v2 = *(const ushort4*)(Hb + (size_t)s4.z * DM + c4);
                ushort4 v3 = *(const ushort4*)(Hb + (size_t)s4.w * DM + c4);
                a0 += bf2f(v0.x) + bf2f(v1.x) + bf2f(v2.x) + bf2f(v3.x);
                a1 += bf2f(v0.y) + bf2f(v1.y) + bf2f(v2.y) + bf2f(v3.y);
                a2 += bf2f(v0.z) + bf2f(v1.z) + bf2f(v2.z) + bf2f(v3.z);
                a3 += bf2f(v0.w) + bf2f(v1.w) + bf2f(v2.w) + bf2f(v3.w);
            }
            for (; j < dg; ++j) {
                int s0 = bk[j];
                ushort4 v0 = *(const ushort4*)(Hb + (size_t)s0 * DM + c4);
                a0 += bf2f(v0.x); a1 += bf2f(v0.y); a2 += bf2f(v0.z); a3 += bf2f(v0.w);
            }
            ushort4 hv;
            hv.x = f2bf(a0); hv.y = f2bf(a1); hv.z = f2bf(a2); hv.w = f2bf(a3);
            *(ushort4*)&Gs[lr][c4] = hv;
        }
        __syncthreads();
        // MFMA: 4 k-tiles; B-frags direct from global Wt (cached)
        const unsigned short* Wrc = Wt + rc * 128;
#pragma unroll
        for (int kt = 0; kt < 4; ++kt) {
            bf16x8 a = *(const bf16x8*)&Gs[w * 16 + lm][kt * 32 + q * 8];
#pragma unroll
            for (int ct = 0; ct < 8; ++ct) {
                bf16x8 bf = *(const bf16x8*)(Wrc + (size_t)(ct * 16 + lm) * 384 + kt * 32 + q * 8);
                acc[ct] = __builtin_amdgcn_mfma_f32_16x16x32_bf16(a, bf, acc[ct], 0, 0, 0);
            }
        }
        __syncthreads();
    }

    // epilogue: x = H + relu(acc + SB); LayerNorm over 128 cols
    float gc[8], bc[8];
#pragma unroll
    for (int ct = 0; ct < 8; ++ct) {
        int col = ct * 16 + lm;
        gc[ct] = lng[col]; bc[ct] = lnb[col];
    }
#pragma unroll
    for (int reg = 0; reg < 4; ++reg) {
        int lr = w * 16 + q * 4 + reg;
        size_t row = row0 + lr;
        int n = n0 + lr;
        float xv[8];
        float s1 = 0.f, s2 = 0.f;
#pragma unroll
        for (int ct = 0; ct < 8; ++ct) {
            int col = ct * 16 + lm;
            float h  = bf2f(HBprev[row * DM + col]);
            float sb = SB[(size_t)n * DM + col];
            float v = h + fmaxf(acc[ct][reg] + sb, 0.f);
            xv[ct] = v; s1 += v; s2 += v * v;
        }
#pragma unroll
        for (int m = 1; m <= 8; m <<= 1) {
            s1 += __shfl_xor(s1, m, 64);
            s2 += __shfl_xor(s2, m, 64);
        }
        float mu  = s1 * (1.f / 128.f);
        float var = s2 * (1.f / 128.f) - mu * mu;
        float inv = rsqrtf(var + LN_EPS);
        if (write_f32) {
#pragma unroll
            for (int ct = 0; ct < 8; ++ct) {
                int col = ct * 16 + lm;
                out[row * DM + col] = (xv[ct] - mu) * inv * gc[ct] + bc[ct];
            }
        } else {
#pragma unroll
            for (int ct = 0; ct < 8; ++ct) {
                int col = ct * 16 + lm;
                HBnext[row * DM + col] = f2bf((xv[ct] - mu) * inv * gc[ct] + bc[ct]);
            }
        }
    }
}

extern "C" void kernel_launch(void* const* d_in, const int* in_sizes, int n_in,
                              void* d_out, int out_size, void* d_ws, size_t ws_size,
                              hipStream_t stream) {
    const float* node_feat = (const float*)d_in[0];
    const float* in_W   = (const float*)d_in[1];
    const float* in_b   = (const float*)d_in[2];
    const float* node_W = (const float*)d_in[3];   // [2][3][128][128]
    const float* node_b = (const float*)d_in[4];   // [2][3][128]
    const float* edge_W = (const float*)d_in[5];   // [2][2][16][128]
    const float* edge_b = (const float*)d_in[6];   // [2][2][128]
    const float* ln_g   = (const float*)d_in[7];   // [2][128]
    const float* ln_b   = (const float*)d_in[8];   // [2][128]
    const float* ea0    = (const float*)d_in[9];
    const float* ea1    = (const float*)d_in[10];
    const int*   ei0    = (const int*)d_in[11];
    const int*   ei1    = (const int*)d_in[12];
    const int*   ei2    = (const int*)d_in[13];
    float* out = (float*)d_out;

    char* ws = (char*)d_ws;
    size_t off = 0;
    auto alloc = [&](size_t bytes) -> void* {
        void* p = ws + off;
        off = (off + bytes + 255) & ~(size_t)255;
        return p;
    };
    unsigned short* HB     = (unsigned short*)alloc((size_t)BROWS * DM * 2);   // 20.5 MB
    unsigned short* HB2    = (unsigned short*)alloc((size_t)BROWS * DM * 2);   // 20.5 MB
    float*          SB     = (float*)alloc((size_t)2 * NNODES * DM * 4);       // 20.5 MB
    int*            cursor = (int*)alloc((size_t)3 * NNODES * 4);              // zeroed
    float*          S      = (float*)alloc((size_t)2 * NNODES * 16 * 4);
    int*            srcs   = (int*)alloc((size_t)3 * NNODES * CAP * 4);        // 15 MB
    int*            eids   = (int*)alloc((size_t)2 * NNODES * CAP * 4);        // 10 MB
    unsigned short* Wt     = (unsigned short*)alloc((size_t)2 * 128 * 384 * 2);

    hipMemsetAsync(cursor, 0, (size_t)3 * NNODES * 4, stream);

    k_scatter<<<(3 * NE + 255) / 256, 256, 0, stream>>>(ei0, ei1, ei2, cursor, srcs, eids);
    k_sgather<<<(2 * NNODES) / 4, 256, 0, stream>>>(cursor, eids, ea0, ea1, S);
    k_wprep<<<384, 256, 0, stream>>>(node_W, Wt);
    k_proj<<<BROWS / 64, 256, 0, stream>>>(node_feat, in_W, in_b, HB);
    k_sb<<<2 * NNODES, 128, 0, stream>>>(cursor, S, node_b, edge_W, edge_b, SB);

    const int grid = 8 * ((TPB + 1) / 2);   // 1256 blocks; 4 return early
    k_fused<<<grid, 256, 0, stream>>>(HB, cursor, srcs, Wt, SB, HB2,
                                      ln_g, ln_b, out, 0);
    k_fused<<<grid, 256, 0, stream>>>(HB2, cursor, srcs, Wt + (size_t)128 * 384,
                                      SB + (size_t)NNODES * DM, HB2 /*unused*/,
                                      ln_g + DM, ln_b + DM, out, 1);
}

// Round 6
// 328.711 us; speedup vs baseline: 1.7965x; 1.7431x over previous
//
#include <hip/hip_runtime.h>

// MultiRelGraphTransformer on MI355X — round 6.
// REVERT to split spmm/gemm (fusion failed twice: r4 occupancy, r5 L2 thrash).
// New vs r3: (a) SB/k_sb eliminated — bias folded into GEMM as 64 ext K-cols
// ([deg0,deg1,deg2,S0[16],S1[16],0...] @ ext rows of Wt), (b) k_proj is MFMA,
// (c) GEMM updates HB in place (HB2 gone), (d) spmm uses 16-lane x dwordx4 rows.

#define NNODES 20000
#define NB     4
#define BROWS  (NB * NNODES)   // 80000
#define DN     64
#define DM     128
#define NE     160000
#define CAP    64              // bucket capacity per (relation,dst); Poisson(8)
#define LN_EPS 1e-5f
#define KE     448             // 384 spmm cols + 64 ext cols
#define LDW    88              // LDS row stride in ushorts: 44 dw -> 2-way (free)

typedef __attribute__((ext_vector_type(8))) short bf16x8;
typedef __attribute__((ext_vector_type(4))) float f32x4;

__device__ inline float bf2f(unsigned short u) {
    union { unsigned int i; float f; } x; x.i = ((unsigned int)u) << 16; return x.f;
}
__device__ inline unsigned short f2bf(float f) {
    union { float f; unsigned int i; } x; x.f = f;
    unsigned int r = x.i + 0x7FFFu + ((x.i >> 16) & 1u);
    return (unsigned short)(r >> 16);
}

// ---------- K1: counting-sort into fixed buckets (cursor = true degree) ----------
__global__ void k_scatter(const int* __restrict__ ei0, const int* __restrict__ ei1,
                          const int* __restrict__ ei2, int* __restrict__ cursor,
                          int* __restrict__ srcs, int* __restrict__ eids) {
    int tid = blockIdx.x * blockDim.x + threadIdx.x;
    if (tid >= 3 * NE) return;
    int r = tid / NE, e = tid - r * NE;
    const int* ei = (r == 0) ? ei0 : ((r == 1) ? ei1 : ei2);
    int src = ei[e], dst = ei[NE + e];
    int p = atomicAdd(&cursor[r * NNODES + dst], 1);
    if (p < CAP) {
        srcs[(r * NNODES + dst) * CAP + p] = src;
        if (r < 2) eids[(r * NNODES + dst) * CAP + p] = e;
    }
}

// ---------- K2: S[r][n][16] = sum of ea_r over incoming edges (bucket walk) ----------
__global__ __launch_bounds__(256) void k_sgather(const int* __restrict__ deg,
                                                 const int* __restrict__ eids,
                                                 const float* __restrict__ ea0,
                                                 const float* __restrict__ ea1,
                                                 float* __restrict__ S) {
    int task = blockIdx.x * 4 + (threadIdx.x >> 6);   // 0 .. 2*NNODES-1
    int r = task / NNODES;
    const float* ea = r ? ea1 : ea0;
    int lane = threadIdx.x & 63;
    int k = lane & 15, sub = lane >> 4;
    int dg = deg[task]; if (dg > CAP) dg = CAP;
    const int* bk = eids + (size_t)task * CAP;
    float acc = 0.f;
    for (int j = sub; j < dg; j += 4) {
        int e = bk[j];
        acc += ea[e * 16 + k];
    }
    acc += __shfl_xor(acc, 16, 64);
    acc += __shfl_xor(acc, 32, 64);
    if (lane < 16) S[(size_t)task * 16 + k] = acc;
}

// ---------- K3: build Wt[2][128][448] (transposed node_W + ext rows) and Wp[128][64] ----------
// ext k=384+kk: kk<3 -> node_b[l][kk]+edge_b[l][kk](kk<2); kk in [3,35) ->
// edge_W[l][(kk-3)>>4][(kk-3)&15]; else 0.  Wp[n][k] = in_W[k][n] (input proj B).
__global__ __launch_bounds__(256) void k_wprep(const float* __restrict__ nW,
                                               const float* __restrict__ nb,
                                               const float* __restrict__ eW,
                                               const float* __restrict__ eb,
                                               const float* __restrict__ inW,
                                               unsigned short* __restrict__ Wt,
                                               unsigned short* __restrict__ Wp) {
    int lin = blockIdx.x * 256 + threadIdx.x;    // 2*128*448 + 128*64 = 122880
    if (lin < 2 * 128 * KE) {
        int l = lin / (128 * KE);
        int rem = lin - l * 128 * KE;
        int n = rem / KE, k = rem - n * KE;
        float v;
        if (k < 384) {
            int r = k >> 7, kk = k & 127;
            v = nW[(((size_t)(l * 3 + r) * 128) + kk) * 128 + n];
        } else {
            int e = k - 384;
            if (e < 3) {
                v = nb[(l * 3 + e) * DM + n];
                if (e < 2) v += eb[(l * 2 + e) * DM + n];
            } else if (e < 35) {
                int r2 = (e - 3) >> 4, j = (e - 3) & 15;
                v = eW[((size_t)((l * 2 + r2) * 16 + j)) * DM + n];
            } else v = 0.f;
        }
        Wt[lin] = f2bf(v);
    } else {
        int i = lin - 2 * 128 * KE;
        int n = i >> 6, k = i & 63;
        Wp[n * 64 + k] = f2bf(inW[(size_t)k * DM + n]);
    }
}

// ---------- K4: input projection HB = bf16(node_feat @ in_W + in_b), MFMA ----------
__global__ __launch_bounds__(256) void k_proj(const float* __restrict__ X,
                                              const unsigned short* __restrict__ Wp,  // [128][64]
                                              const float* __restrict__ bias,
                                              unsigned short* __restrict__ HB) {
    __shared__ __align__(16) unsigned short As[64][LDW];
    __shared__ __align__(16) unsigned short Bs[128][LDW];
    int t = threadIdx.x;
    int m0 = blockIdx.x * 64;
    // stage A: 64x64 fp32 -> bf16
#pragma unroll
    for (int i = 0; i < 4; ++i) {
        int lin = t + 256 * i;                 // 0..1023 (64 rows x 16 float4-segs)
        int row = lin >> 4, seg = lin & 15;
        float4 v = *(const float4*)(X + (size_t)(m0 + row) * DN + seg * 4);
        ushort4 h; h.x = f2bf(v.x); h.y = f2bf(v.y); h.z = f2bf(v.z); h.w = f2bf(v.w);
        *(ushort4*)&As[row][seg * 4] = h;
    }
    // stage B: 128x64 bf16
#pragma unroll
    for (int i = 0; i < 4; ++i) {
        int lin = t + 256 * i;                 // 0..1023 (128 rows x 8 uint4-segs)
        int row = lin >> 3, seg = lin & 7;
        *(uint4*)&Bs[row][seg * 8] = *(const uint4*)(Wp + (size_t)row * 64 + seg * 8);
    }
    __syncthreads();
    int w = t >> 6, lane = t & 63;
    int q = lane >> 4, lm = lane & 15;
    f32x4 acc[8];
#pragma unroll
    for (int ct = 0; ct < 8; ++ct) acc[ct] = (f32x4){0.f, 0.f, 0.f, 0.f};
#pragma unroll
    for (int kt = 0; kt < 2; ++kt) {
        bf16x8 a = *(const bf16x8*)&As[w * 16 + lm][kt * 32 + q * 8];
#pragma unroll
        for (int ct = 0; ct < 8; ++ct) {
            bf16x8 bf = *(const bf16x8*)&Bs[ct * 16 + lm][kt * 32 + q * 8];
            acc[ct] = __builtin_amdgcn_mfma_f32_16x16x32_bf16(a, bf, acc[ct], 0, 0, 0);
        }
    }
#pragma unroll
    for (int reg = 0; reg < 4; ++reg) {
        int row = m0 + w * 16 + q * 4 + reg;
#pragma unroll
        for (int ct = 0; ct < 8; ++ct) {
            int col = ct * 16 + lm;
            HB[(size_t)row * DM + col] = f2bf(acc[ct][reg] + bias[col]);
        }
    }
}

// ---------- K5: SpMM + ext-col write ----------
// Block = 16 nodes x 1 batch (XCD affinity). 16 lanes x dwordx4 per row.
// G[row][r*128+c] = rel-sum; G[row][384..448] = [deg0,deg1,deg2,S0,S1,0..] bf16.
__global__ __launch_bounds__(256) void k_spmm(const unsigned short* __restrict__ HB,
                                              const int* __restrict__ deg,
                                              const int* __restrict__ srcs,
                                              const float* __restrict__ S,
                                              unsigned short* __restrict__ G) {
    int blk = blockIdx.x;                      // 5000
    int s = blk & 7;
    int bb = s >> 1;                           // xcd -> batch
    int idx = ((blk >> 3) << 1) + (s & 1);     // [0,1250)
    int n0 = idx * 16;
    int g = threadIdx.x >> 4, lane = threadIdx.x & 15;
    int n = n0 + g;
    int c8 = lane * 8;                         // ushort offset; 16 B per lane
    const unsigned short* Hb = HB + (size_t)bb * NNODES * DM;
    size_t rowbase = ((size_t)(bb * NNODES + n)) * KE;
    int dt[3];
#pragma unroll
    for (int r = 0; r < 3; ++r) {
        dt[r] = deg[r * NNODES + n];
        int dg = dt[r] > CAP ? CAP : dt[r];
        const int* bk = srcs + (size_t)(r * NNODES + n) * CAP;
        float a[8];
#pragma unroll
        for (int j = 0; j < 8; ++j) a[j] = 0.f;
        int j = 0;
        for (; j + 3 < dg; j += 4) {
            int4 s4 = *(const int4*)&bk[j];
            ushort4 u0 = *(const ushort4*)(Hb + (size_t)s4.x * DM + c8);
            ushort4 u1 = *(const ushort4*)(Hb + (size_t)s4.x * DM + c8 + 4);
            ushort4 v0 = *(const ushort4*)(Hb + (size_t)s4.y * DM + c8);
            ushort4 v1 = *(const ushort4*)(Hb + (size_t)s4.y * DM + c8 + 4);
            ushort4 w0 = *(const ushort4*)(Hb + (size_t)s4.z * DM + c8);
            ushort4 w1 = *(const ushort4*)(Hb + (size_t)s4.z * DM + c8 + 4);
            ushort4 x0 = *(const ushort4*)(Hb + (size_t)s4.w * DM + c8);
            ushort4 x1 = *(const ushort4*)(Hb + (size_t)s4.w * DM + c8 + 4);
            a[0] += bf2f(u0.x) + bf2f(v0.x) + bf2f(w0.x) + bf2f(x0.x);
            a[1] += bf2f(u0.y) + bf2f(v0.y) + bf2f(w0.y) + bf2f(x0.y);
            a[2] += bf2f(u0.z) + bf2f(v0.z) + bf2f(w0.z) + bf2f(x0.z);
            a[3] += bf2f(u0.w) + bf2f(v0.w) + bf2f(w0.w) + bf2f(x0.w);
            a[4] += bf2f(u1.x) + bf2f(v1.x) + bf2f(w1.x) + bf2f(x1.x);
            a[5] += bf2f(u1.y) + bf2f(v1.y) + bf2f(w1.y) + bf2f(x1.y);
            a[6] += bf2f(u1.z) + bf2f(v1.z) + bf2f(w1.z) + bf2f(x1.z);
            a[7] += bf2f(u1.w) + bf2f(v1.w) + bf2f(w1.w) + bf2f(x1.w);
        }
        for (; j < dg; ++j) {
            int s0 = bk[j];
            ushort4 u0 = *(const ushort4*)(Hb + (size_t)s0 * DM + c8);
            ushort4 u1 = *(const ushort4*)(Hb + (size_t)s0 * DM + c8 + 4);
            a[0] += bf2f(u0.x); a[1] += bf2f(u0.y); a[2] += bf2f(u0.z); a[3] += bf2f(u0.w);
            a[4] += bf2f(u1.x); a[5] += bf2f(u1.y); a[6] += bf2f(u1.z); a[7] += bf2f(u1.w);
        }
        ushort4 o0, o1;
        o0.x = f2bf(a[0]); o0.y = f2bf(a[1]); o0.z = f2bf(a[2]); o0.w = f2bf(a[3]);
        o1.x = f2bf(a[4]); o1.y = f2bf(a[5]); o1.z = f2bf(a[6]); o1.w = f2bf(a[7]);
        *(ushort4*)(G + rowbase + r * 128 + c8) = o0;
        *(ushort4*)(G + rowbase + r * 128 + c8 + 4) = o1;
    }
    // ext cols: lanes 0..7 write 8 bf16 each -> kk = lane*8+j
    if (lane < 8) {
        ushort4 e0, e1;
        unsigned short ev[8];
#pragma unroll
        for (int j = 0; j < 8; ++j) {
            int kk = lane * 8 + j;
            float v;
            if (kk < 3)       v = (float)dt[kk];
            else if (kk < 19) v = S[((size_t)(0 * NNODES + n)) * 16 + (kk - 3)];
            else if (kk < 35) v = S[((size_t)(1 * NNODES + n)) * 16 + (kk - 19)];
            else              v = 0.f;
            ev[j] = f2bf(v);
        }
        e0.x = ev[0]; e0.y = ev[1]; e0.z = ev[2]; e0.w = ev[3];
        e1.x = ev[4]; e1.y = ev[5]; e1.z = ev[6]; e1.w = ev[7];
        *(ushort4*)(G + rowbase + 384 + lane * 8) = e0;
        *(ushort4*)(G + rowbase + 384 + lane * 8 + 4) = e1;
    }
}

// ---------- K6: bf16 MFMA GEMM [64x448]@[448x128] + residual + ReLU + LN ----------
// A-frag A[m=lane&15][k=q*8+j]; C/D col=lane&15, row=(lane>>4)*4+reg.
// In-place residual: each lane reads HB[row][col] before writing it.
__global__ __launch_bounds__(256) void k_gemm_ln(const unsigned short* __restrict__ G,   // [BROWS][448]
                                                 const unsigned short* __restrict__ Wt,  // [128][448]
                                                 unsigned short* HB,
                                                 const float* __restrict__ lng,
                                                 const float* __restrict__ lnb,
                                                 float* __restrict__ out, int write_f32) {
    __shared__ __align__(16) unsigned short Gs[64][LDW];
    __shared__ __align__(16) unsigned short Ws[128][LDW];
    int t = threadIdx.x;
    int m0 = blockIdx.x * 64;
    int w = t >> 6, lane = t & 63;
    int q = lane >> 4, lm = lane & 15;

    f32x4 acc[8];
#pragma unroll
    for (int ct = 0; ct < 8; ++ct) acc[ct] = (f32x4){0.f, 0.f, 0.f, 0.f};

    for (int kc = 0; kc < 7; ++kc) {
        // stage G chunk: 64 rows x 64 k (512 uint4)
#pragma unroll
        for (int i = 0; i < 2; ++i) {
            int lin = t + 256 * i;
            int row = lin >> 3, seg = lin & 7;
            *(uint4*)&Gs[row][seg * 8] =
                *(const uint4*)(G + (size_t)(m0 + row) * KE + kc * 64 + seg * 8);
        }
        // stage Wt chunk: 128 rows x 64 k (1024 uint4)
#pragma unroll
        for (int i = 0; i < 4; ++i) {
            int lin = t + 256 * i;
            int row = lin >> 3, seg = lin & 7;
            *(uint4*)&Ws[row][seg * 8] =
                *(const uint4*)(Wt + (size_t)row * KE + kc * 64 + seg * 8);
        }
        __syncthreads();
#pragma unroll
        for (int kt = 0; kt < 2; ++kt) {
            bf16x8 a = *(const bf16x8*)&Gs[w * 16 + lm][kt * 32 + q * 8];
#pragma unroll
            for (int ct = 0; ct < 8; ++ct) {
                bf16x8 bf = *(const bf16x8*)&Ws[ct * 16 + lm][kt * 32 + q * 8];
                acc[ct] = __builtin_amdgcn_mfma_f32_16x16x32_bf16(a, bf, acc[ct], 0, 0, 0);
            }
        }
        __syncthreads();
    }

    float gc[8], bc[8];
#pragma unroll
    for (int ct = 0; ct < 8; ++ct) {
        int col = ct * 16 + lm;
        gc[ct] = lng[col]; bc[ct] = lnb[col];
    }
#pragma unroll
    for (int reg = 0; reg < 4; ++reg) {
        size_t row = (size_t)m0 + w * 16 + q * 4 + reg;
        float xv[8];
        float s1 = 0.f, s2 = 0.f;
#pragma unroll
        for (int ct = 0; ct < 8; ++ct) {
            int col = ct * 16 + lm;
            float h = bf2f(HB[row * DM + col]);
            float v = h + fmaxf(acc[ct][reg], 0.f);
            xv[ct] = v; s1 += v; s2 += v * v;
        }
#pragma unroll
        for (int m = 1; m <= 8; m <<= 1) {
            s1 += __shfl_xor(s1, m, 64);
            s2 += __shfl_xor(s2, m, 64);
        }
        float mu  = s1 * (1.f / 128.f);
        float var = s2 * (1.f / 128.f) - mu * mu;
        float inv = rsqrtf(var + LN_EPS);
        if (write_f32) {
#pragma unroll
            for (int ct = 0; ct < 8; ++ct) {
                int col = ct * 16 + lm;
                out[row * DM + col] = (xv[ct] - mu) * inv * gc[ct] + bc[ct];
            }
        } else {
#pragma unroll
            for (int ct = 0; ct < 8; ++ct) {
                int col = ct * 16 + lm;
                HB[row * DM + col] = f2bf((xv[ct] - mu) * inv * gc[ct] + bc[ct]);
            }
        }
    }
}

extern "C" void kernel_launch(void* const* d_in, const int* in_sizes, int n_in,
                              void* d_out, int out_size, void* d_ws, size_t ws_size,
                              hipStream_t stream) {
    const float* node_feat = (const float*)d_in[0];
    const float* in_W   = (const float*)d_in[1];
    const float* in_b   = (const float*)d_in[2];
    const float* node_W = (const float*)d_in[3];   // [2][3][128][128]
    const float* node_b = (const float*)d_in[4];   // [2][3][128]
    const float* edge_W = (const float*)d_in[5];   // [2][2][16][128]
    const float* edge_b = (const float*)d_in[6];   // [2][2][128]
    const float* ln_g   = (const float*)d_in[7];   // [2][128]
    const float* ln_b   = (const float*)d_in[8];   // [2][128]
    const float* ea0    = (const float*)d_in[9];
    const float* ea1    = (const float*)d_in[10];
    const int*   ei0    = (const int*)d_in[11];
    const int*   ei1    = (const int*)d_in[12];
    const int*   ei2    = (const int*)d_in[13];
    float* out = (float*)d_out;

    char* ws = (char*)d_ws;
    size_t off = 0;
    auto alloc = [&](size_t bytes) -> void* {
        void* p = ws + off;
        off = (off + bytes + 255) & ~(size_t)255;
        return p;
    };
    unsigned short* HB     = (unsigned short*)alloc((size_t)BROWS * DM * 2);   // 20.5 MB
    unsigned short* G      = (unsigned short*)alloc((size_t)BROWS * KE * 2);   // 71.7 MB
    int*            cursor = (int*)alloc((size_t)3 * NNODES * 4);              // zeroed
    float*          S      = (float*)alloc((size_t)2 * NNODES * 16 * 4);
    int*            srcs   = (int*)alloc((size_t)3 * NNODES * CAP * 4);        // 15.4 MB
    int*            eids   = (int*)alloc((size_t)2 * NNODES * CAP * 4);        // 10.2 MB
    unsigned short* Wt     = (unsigned short*)alloc((size_t)2 * 128 * KE * 2);
    unsigned short* Wp     = (unsigned short*)alloc((size_t)128 * 64 * 2);

    hipMemsetAsync(cursor, 0, (size_t)3 * NNODES * 4, stream);

    k_scatter<<<(3 * NE + 255) / 256, 256, 0, stream>>>(ei0, ei1, ei2, cursor, srcs, eids);
    k_sgather<<<(2 * NNODES) / 4, 256, 0, stream>>>(cursor, eids, ea0, ea1, S);
    k_wprep<<<480, 256, 0, stream>>>(node_W, node_b, edge_W, edge_b, in_W, Wt, Wp);
    k_proj<<<BROWS / 64, 256, 0, stream>>>(node_feat, Wp, in_b, HB);

    for (int l = 0; l < 2; ++l) {
        k_spmm<<<5000, 256, 0, stream>>>(HB, cursor, srcs, S, G);
        k_gemm_ln<<<BROWS / 64, 256, 0, stream>>>(G, Wt + (size_t)l * 128 * KE, HB,
                                                  ln_g + (size_t)l * DM, ln_b + (size_t)l * DM,
                                                  out, l == 1);
    }
}